// Round 7
// baseline (88.232 us; speedup 1.0000x reference)
//
#include <hip/hip_runtime.h>

#define NMAX   64
#define NSITES 12
#define SPLIT  4      // threads per batch element (3 sites each)
#define BLOCK  256
#define RS     68     // LDS row stride (floats): rows 16B-aligned; the 4
                      // site rows read per wave-op start at banks
                      // {0,12,24,4} (+s*4) -> disjoint b128 spans

#define B_SOFT 0.01f
#define PAD_C  4.0e4f   // sentinel coord -> r2 ~ 3e9 -> med3-clamped to 248
#define R2_LO  9.094947017729282e-13f  // 2^-40: f there = 100.0 - 0.01
#define R2_MAX 248.0f   // top of table range (bits 0x43780000 -> last bin)
#define TBL_LO 1392     // (bits >> 19) of 2^-40
#define TBL_N  768      // bins 1392..2159, 16 per octave, 48 octaves

// f(r2) = exp(-sqrt(r2)) / (sqrt(r2) + b)  (build-time only)
__device__ __forceinline__ float f_exact(float r2) {
    const float r = sqrtf(r2);
    return expf(-r) / (r + B_SOFT);
}

__global__ __launch_bounds__(BLOCK, 8)
void pot_energy_kernel(const float* __restrict__ x,
                       const float* __restrict__ neighbors,
                       const float* __restrict__ mask,
                       float* __restrict__ out, int B) {
    // Split-table layout: c at [idx], s at [idx + TBL_N] -> two random
    // ds_read_b32 from one address (imm offset 4*TBL_N) instead of one
    // random ds_read_b64 (b64 puts 64 lanes on 16 bank-PAIRS; b32 uses
    // all 32 banks and 2-way aliasing is free).
    __shared__ float tblCS[2 * TBL_N];
    __shared__ float nbx[NSITES][RS];
    __shared__ float nby[NSITES][RS];
    __shared__ int   cnt[NSITES];

    const int tid  = threadIdx.x;
    const int wv   = tid >> 6;
    const int lane = tid & 63;

    // Build the piecewise-linear table: f ~= c + s*r2 within each bin,
    // chord with midpoint correction. Bin i: r2 in [bits(i+LO)<<19, next).
    for (int i = tid; i < TBL_N; i += BLOCK) {
        const unsigned ii = (unsigned)(i + TBL_LO);
        const float b0 = __builtin_bit_cast(float, ii << 19);
        const float b1 = __builtin_bit_cast(float, (ii + 1u) << 19);
        const float f0 = f_exact(b0);
        const float f1 = f_exact(b1);
        const float fm = f_exact(0.5f * (b0 + b1));
        const float s  = (f1 - f0) / (b1 - b0);
        const float c  = f0 - s * b0 - 0.5f * (0.5f * (f0 + f1) - fm);
        tblCS[i]         = c;
        tblCS[i + TBL_N] = s;
    }

    // Sentinel fill: iterations past a site's compacted count give huge r2
    // -> clamped to last bin -> contribute ~1e-8 each.
    for (int idx = tid; idx < NSITES * RS; idx += BLOCK) {
        const int s = idx / RS, j = idx - s * RS;
        nbx[s][j] = PAD_C;
        nby[s][j] = PAD_C;
    }
    __syncthreads();

    // Ballot-compaction of neighbor lists into SoA LDS (~64 -> ~58).
    for (int s = wv; s < NSITES; s += 4) {
        const bool keep = mask[s * NMAX + lane] > 0.5f;
        const unsigned long long bal = __ballot(keep);
        if (keep) {
            const int pos = __popcll(bal & ((1ull << lane) - 1ull));
            const float2 p = ((const float2*)neighbors)[s * NMAX + lane];
            nbx[s][pos] = p.x;
            nby[s][pos] = p.y;
        }
        if (lane == 0) cnt[s] = __popcll(bal);
    }
    __syncthreads();

    // Uniform loop bound: max count over all sites (identical in every lane).
    int m = 0;
    #pragma unroll
    for (int s = 0; s < NSITES; ++s) m = max(m, cnt[s]);
    m = (__builtin_amdgcn_readfirstlane(m) + 3) & ~3;   // <= 64, RS-safe

    const int gtid = blockIdx.x * BLOCK + tid;
    const int e = gtid >> 2;
    const int q = gtid & 3;
    if (e >= B) return;

    const float2* xp = (const float2*)(x + (size_t)gtid * 6);
    const float2 p0 = xp[0], p1 = xp[1], p2 = xp[2];
    const float xs_[3] = { p0.x, p1.x, p2.x };
    const float ys_[3] = { p0.y, p1.y, p2.y };

    float accC = 0.f, accS = 0.f;   // sum(c_i) and sum(s_i * r2_i)
    #pragma unroll
    for (int s = 0; s < 3; ++s) {
        const int site = q * 3 + s;
        const float xs = xs_[s];
        const float ys = ys_[s];
        const float* __restrict__ rx = nbx[site];
        const float* __restrict__ ry = nby[site];
        #pragma unroll 2
        for (int j0 = 0; j0 < m; j0 += 4) {
            const float4 nx4 = *(const float4*)(rx + j0);
            const float4 ny4 = *(const float4*)(ry + j0);
            const float nx[4] = { nx4.x, nx4.y, nx4.z, nx4.w };
            const float ny[4] = { ny4.x, ny4.y, ny4.z, ny4.w };
            #pragma unroll
            for (int k = 0; k < 4; ++k) {
                const float dx = xs - nx[k];
                const float dy = ys - ny[k];
                const float r2r = fmaf(dy, dy, dx * dx);
                // one-instruction two-sided clamp (also catches sentinels
                // high and degenerate tiny r2 low -> idx always in range)
                const float r2 = __builtin_amdgcn_fmed3f(r2r, R2_LO, R2_MAX);
                const unsigned bits = __builtin_bit_cast(unsigned, r2);
                const int idx = (int)(bits >> 19) - TBL_LO;
                const float c = tblCS[idx];          // random ds_read_b32
                const float sl = tblCS[idx + TBL_N]; // same addr, +3072 off
                accC += c;
                accS = fmaf(sl, r2, accS);
            }
        }
    }

    float acc = accC + accS;
    acc += __shfl_xor(acc, 1);   // combine the 4 partials of element e
    acc += __shfl_xor(acc, 2);
    if (q == 0) out[e] = acc;
}

extern "C" void kernel_launch(void* const* d_in, const int* in_sizes, int n_in,
                              void* d_out, int out_size, void* d_ws, size_t ws_size,
                              hipStream_t stream) {
    const float* x   = (const float*)d_in[0];
    const float* nbr = (const float*)d_in[1];
    const float* msk = (const float*)d_in[2];
    float* out = (float*)d_out;

    const int B = in_sizes[0] / 24;
    const int total_threads = B * SPLIT;
    const int blocks = (total_threads + BLOCK - 1) / BLOCK;
    pot_energy_kernel<<<blocks, BLOCK, 0, stream>>>(x, nbr, msk, out, B);
}

// Round 8
// 87.717 us; speedup vs baseline: 1.0059x; 1.0059x over previous
//
#include <hip/hip_runtime.h>

#define NMAX   64
#define NSITES 12
#define SPLIT  4      // threads per batch element (3 sites each)
#define BLOCK  256
#define RS     68     // LDS row stride (floats): rows 16B-aligned; the 4
                      // site rows per wave-op start at disjoint bank spans

#define B_SOFT 0.01f
#define PAD_C  4.0e4f   // sentinel coord -> r2 ~ 3e9 -> med3-clamped to 248
#define R2_LO  9.094947017729282e-13f  // 2^-40
#define R2_MAX 248.0f   // bits 0x43780000 -> last bin (index 2159)
#define TBL_LO 1392     // (bits >> 19) of 2^-40
#define TBL_N  768      // bins 1392..2159, 16 per octave
#define NB_FLOATS (NSITES * RS)        // 816
#define TBL_BASE  (2 * NB_FLOATS)      // table starts at dword 1632

// f(r2) = exp(-sqrt(r2)) / (sqrt(r2) + b)  (table build only)
__device__ __forceinline__ float f_exact(float r2) {
    const float r = sqrtf(r2);
    return expf(-r) / (r + B_SOFT);
}
__device__ __forceinline__ unsigned to_bf16_rne(float v) {
    const unsigned b = __builtin_bit_cast(unsigned, v);
    return (b + 0x7FFFu + ((b >> 16) & 1u)) >> 16;
}

__global__ __launch_bounds__(BLOCK, 8)
void pot_energy_kernel(const float* __restrict__ x,
                       const float* __restrict__ neighbors,
                       const float* __restrict__ mask,
                       float* __restrict__ out, int B) {
    // One LDS buffer: [0,816) nbx rows, [816,1632) nby rows,
    // [1632,2400) packed table (bf16 fb | bf16 s per dword).
    __shared__ unsigned ldsbuf[TBL_BASE + TBL_N];
    __shared__ int cnt[NSITES];

    float* nbx = (float*)ldsbuf;
    float* nby = (float*)ldsbuf + NB_FLOATS;

    const int tid  = threadIdx.x;
    const int wv   = tid >> 6;
    const int lane = tid & 63;

    // Build packed table: f ~= fb + s*dr on each bin, dr = r2 - bin_base.
    // fb is equioscillation-shifted so |err| is halved vs plain chord.
    for (int i = tid; i < TBL_N; i += BLOCK) {
        const unsigned ii = (unsigned)(i + TBL_LO);
        const float b0 = __builtin_bit_cast(float, ii << 19);
        const float b1 = __builtin_bit_cast(float, (ii + 1u) << 19);
        const float f0 = f_exact(b0);
        const float f1 = f_exact(b1);
        const float fm = f_exact(0.5f * (b0 + b1));
        const float s  = (f1 - f0) / (b1 - b0);
        const float fb = f0 - 0.5f * (0.5f * (f0 + f1) - fm);
        ldsbuf[TBL_BASE + i] = (to_bf16_rne(fb) << 16) | to_bf16_rne(s);
    }

    // Sentinel fill: entries past a site's compacted count give huge r2
    // -> clamped to last bin -> contribute ~1e-8 each.
    for (int idx = tid; idx < NB_FLOATS; idx += BLOCK) {
        nbx[idx] = PAD_C;
        nby[idx] = PAD_C;
    }
    __syncthreads();

    // Ballot-compaction of neighbor lists into SoA LDS (~64 -> ~58).
    for (int s = wv; s < NSITES; s += 4) {
        const bool keep = mask[s * NMAX + lane] > 0.5f;
        const unsigned long long bal = __ballot(keep);
        if (keep) {
            const int pos = __popcll(bal & ((1ull << lane) - 1ull));
            const float2 p = ((const float2*)neighbors)[s * NMAX + lane];
            nbx[s * RS + pos] = p.x;
            nby[s * RS + pos] = p.y;
        }
        if (lane == 0) cnt[s] = __popcll(bal);
    }
    __syncthreads();

    // Uniform loop bound: max count over all sites (identical in all lanes).
    int m = 0;
    #pragma unroll
    for (int s = 0; s < NSITES; ++s) m = max(m, cnt[s]);
    m = (__builtin_amdgcn_readfirstlane(m) + 3) & ~3;   // <= 64, RS-safe

    const int gtid = blockIdx.x * BLOCK + tid;
    const int e = gtid >> 2;
    const int q = gtid & 3;
    if (e >= B) return;

    const float2* xp = (const float2*)(x + (size_t)gtid * 6);
    const float2 p0 = xp[0], p1 = xp[1], p2 = xp[2];
    const float xs_[3] = { p0.x, p1.x, p2.x };
    const float ys_[3] = { p0.y, p1.y, p2.y };

    float aC0 = 0.f, aC1 = 0.f;   // sum(fb)
    float aS0 = 0.f, aS1 = 0.f;   // sum(s * dr)
    #pragma unroll
    for (int s = 0; s < 3; ++s) {
        const int site = q * 3 + s;
        const float xs = xs_[s];
        const float ys = ys_[s];
        const float* __restrict__ rx = nbx + site * RS;
        const float* __restrict__ ry = nby + site * RS;
        #pragma unroll 2
        for (int j0 = 0; j0 < m; j0 += 4) {
            const float4 nx4 = *(const float4*)(rx + j0);
            const float4 ny4 = *(const float4*)(ry + j0);
            const float nx[4] = { nx4.x, nx4.y, nx4.z, nx4.w };
            const float ny[4] = { ny4.x, ny4.y, ny4.z, ny4.w };
            #pragma unroll
            for (int k = 0; k < 4; ++k) {
                const float dx = xs - nx[k];
                const float dy = ys - ny[k];
                const float r2r = fmaf(dy, dy, dx * dx);
                const float r2 = __builtin_amdgcn_fmed3f(r2r, R2_LO, R2_MAX);
                const unsigned bits = __builtin_bit_cast(unsigned, r2);
                // single random ds_read_b32 (bias folded into the constant)
                const unsigned pk =
                    ldsbuf[(bits >> 19) + (TBL_BASE - TBL_LO)];
                const float bb =
                    __builtin_bit_cast(float, bits & 0xFFF80000u);
                const float dr = r2 - bb;
                const float fb =
                    __builtin_bit_cast(float, pk & 0xFFFF0000u);
                const float sl = __builtin_bit_cast(float, pk << 16);
                if (k & 1) { aC1 += fb; aS1 = fmaf(sl, dr, aS1); }
                else       { aC0 += fb; aS0 = fmaf(sl, dr, aS0); }
            }
        }
    }

    float acc = (aC0 + aC1) + (aS0 + aS1);
    acc += __shfl_xor(acc, 1);   // combine the 4 partials of element e
    acc += __shfl_xor(acc, 2);
    if (q == 0) out[e] = acc;
}

extern "C" void kernel_launch(void* const* d_in, const int* in_sizes, int n_in,
                              void* d_out, int out_size, void* d_ws, size_t ws_size,
                              hipStream_t stream) {
    const float* x   = (const float*)d_in[0];
    const float* nbr = (const float*)d_in[1];
    const float* msk = (const float*)d_in[2];
    float* out = (float*)d_out;

    const int B = in_sizes[0] / 24;
    const int total_threads = B * SPLIT;
    const int blocks = (total_threads + BLOCK - 1) / BLOCK;
    pot_energy_kernel<<<blocks, BLOCK, 0, stream>>>(x, nbr, msk, out, B);
}

// Round 9
// 84.316 us; speedup vs baseline: 1.0464x; 1.0403x over previous
//
#include <hip/hip_runtime.h>

#define NMAX   64
#define NSITES 12
#define SPLIT  4      // threads per ELEMENT-PAIR slot (3 sites each)
#define ELEMS  2      // elements per thread: one row b128 read feeds 8 ints
#define BLOCK  256
#define RS     68     // LDS row stride (floats): rows 16B-aligned

#define B_SOFT 0.01f
#define PAD_C  4.0e4f   // sentinel coord -> r2 ~ 3e9 -> med3-clamped to 248
#define R2_LO  9.094947017729282e-13f  // 2^-40
#define R2_MAX 248.0f   // bits 0x43780000 -> last bin (idx 767)
#define TBL_LO 1392     // (bits >> 19) of 2^-40
#define TBL_N  768      // 16 bins/octave, 48 octaves

// f(r2) = exp(-sqrt(r2)) / (sqrt(r2) + b)  (table build only)
__device__ __forceinline__ float f_exact(float r2) {
    const float r = sqrtf(r2);
    return expf(-r) / (r + B_SOFT);
}

__global__ __launch_bounds__(BLOCK, 4)
void pot_energy_kernel(const float* __restrict__ x,
                       const float* __restrict__ neighbors,
                       const float* __restrict__ mask,
                       float* __restrict__ out, int B) {
    __shared__ float2 tbl[TBL_N];     // (c, s): f ~= c + s*r2 in the bin
    __shared__ float  nbx[NSITES][RS];
    __shared__ float  nby[NSITES][RS];
    __shared__ int    cnt[NSITES];

    const int tid  = threadIdx.x;
    const int wv   = tid >> 6;
    const int lane = tid & 63;

    // Piecewise-linear table, chord + midpoint correction (R6 verbatim).
    for (int i = tid; i < TBL_N; i += BLOCK) {
        const unsigned ii = (unsigned)(i + TBL_LO);
        const float b0 = __builtin_bit_cast(float, ii << 19);
        const float b1 = __builtin_bit_cast(float, (ii + 1u) << 19);
        const float f0 = f_exact(b0);
        const float f1 = f_exact(b1);
        const float fm = f_exact(0.5f * (b0 + b1));
        const float s  = (f1 - f0) / (b1 - b0);
        const float c  = f0 - s * b0 - 0.5f * (0.5f * (f0 + f1) - fm);
        tbl[i] = make_float2(c, s);
    }

    // Sentinel fill: entries past a site's count -> clamped -> ~1e-8 each.
    for (int idx = tid; idx < NSITES * RS; idx += BLOCK) {
        const int s = idx / RS, j = idx - s * RS;
        nbx[s][j] = PAD_C;
        nby[s][j] = PAD_C;
    }
    __syncthreads();

    // Ballot-compaction of neighbor lists into SoA LDS (~64 -> ~58).
    for (int s = wv; s < NSITES; s += 4) {
        const bool keep = mask[s * NMAX + lane] > 0.5f;
        const unsigned long long bal = __ballot(keep);
        if (keep) {
            const int pos = __popcll(bal & ((1ull << lane) - 1ull));
            const float2 p = ((const float2*)neighbors)[s * NMAX + lane];
            nbx[s][pos] = p.x;
            nby[s][pos] = p.y;
        }
        if (lane == 0) cnt[s] = __popcll(bal);
    }
    __syncthreads();

    // Uniform loop bound (identical in all lanes), multiple of 4.
    int m = 0;
    #pragma unroll
    for (int s = 0; s < NSITES; ++s) m = max(m, cnt[s]);
    m = (__builtin_amdgcn_readfirstlane(m) + 3) & ~3;   // <= 64

    const int gtid = blockIdx.x * BLOCK + tid;
    const int p    = gtid >> 2;   // pair id
    const int q    = gtid & 3;    // 3-site group
    const int half = B / ELEMS;
    if (p >= half) return;
    const int e0 = p;             // stride-split pairing keeps both x-load
    const int e1 = p + half;      // streams and both out-stores coalesced

    float xs_[ELEMS][3], ys_[ELEMS][3];
    #pragma unroll
    for (int t = 0; t < ELEMS; ++t) {
        const int e = (t == 0) ? e0 : e1;
        const float2* xp = (const float2*)(x + (size_t)e * 24 + q * 6);
        const float2 p0 = xp[0], p1 = xp[1], p2 = xp[2];
        xs_[t][0] = p0.x; xs_[t][1] = p1.x; xs_[t][2] = p2.x;
        ys_[t][0] = p0.y; ys_[t][1] = p1.y; ys_[t][2] = p2.y;
    }

    float accC[ELEMS] = {0.f, 0.f}, accS[ELEMS] = {0.f, 0.f};
    #pragma unroll
    for (int s = 0; s < 3; ++s) {
        const int site = q * 3 + s;
        const float* __restrict__ rx = nbx[site];
        const float* __restrict__ ry = nby[site];
        for (int j0 = 0; j0 < m; j0 += 4) {
            // ONE row read pair feeds ELEMS*4 = 8 interactions.
            const float4 nx4 = *(const float4*)(rx + j0);
            const float4 ny4 = *(const float4*)(ry + j0);
            const float nx[4] = { nx4.x, nx4.y, nx4.z, nx4.w };
            const float ny[4] = { ny4.x, ny4.y, ny4.z, ny4.w };
            #pragma unroll
            for (int t = 0; t < ELEMS; ++t) {
                const float xs = xs_[t][s];
                const float ys = ys_[t][s];
                #pragma unroll
                for (int k = 0; k < 4; ++k) {
                    const float dx = xs - nx[k];
                    const float dy = ys - ny[k];
                    const float r2r = fmaf(dy, dy, dx * dx);
                    // one-instruction two-sided clamp (sentinels high,
                    // degenerate tiny r2 low) -> idx always in [0,768)
                    const float r2 =
                        __builtin_amdgcn_fmed3f(r2r, R2_LO, R2_MAX);
                    const unsigned bits = __builtin_bit_cast(unsigned, r2);
                    const int idx = (int)(bits >> 19) - TBL_LO;
                    const float2 cs = tbl[idx];     // random ds_read_b64
                    accC[t] += cs.x;
                    accS[t] = fmaf(cs.y, r2, accS[t]);
                }
            }
        }
    }

    #pragma unroll
    for (int t = 0; t < ELEMS; ++t) {
        float acc = accC[t] + accS[t];
        acc += __shfl_xor(acc, 1);   // combine q=0..3 partials
        acc += __shfl_xor(acc, 2);
        if (q == 0) out[(t == 0) ? e0 : e1] = acc;
    }
}

extern "C" void kernel_launch(void* const* d_in, const int* in_sizes, int n_in,
                              void* d_out, int out_size, void* d_ws, size_t ws_size,
                              hipStream_t stream) {
    const float* x   = (const float*)d_in[0];
    const float* nbr = (const float*)d_in[1];
    const float* msk = (const float*)d_in[2];
    float* out = (float*)d_out;

    const int B = in_sizes[0] / 24;
    const int total_threads = (B / ELEMS) * SPLIT;
    const int blocks = (total_threads + BLOCK - 1) / BLOCK;
    pot_energy_kernel<<<blocks, BLOCK, 0, stream>>>(x, nbr, msk, out, B);
}